// Round 3
// baseline (349.411 us; speedup 1.0000x reference)
//
#include <hip/hip_runtime.h>
#include <hip/hip_bf16.h>

typedef __attribute__((ext_vector_type(8))) short bf16x8;
typedef __attribute__((ext_vector_type(4))) float f32x4;

constexpr int Bb = 32, Kk = 8, Ss = 512, HS = 256;
constexpr int MT = 32;                    // rows per expert tile
constexpr int NST = Ss / MT;              // 16 st tiles per (b,k)
constexpr int TILE_BYTES = MT * HS * 2;   // 16 KB bf16 tile

__device__ __forceinline__ unsigned short f2bf(float f) {
  unsigned int u = __builtin_bit_cast(unsigned int, f);
  u = (u + 0x7FFFu + ((u >> 16) & 1u)) >> 16;
  return (unsigned short)u;
}

__device__ __forceinline__ void gload_lds16(const void* g, void* l) {
  __builtin_amdgcn_global_load_lds((const __attribute__((address_space(1))) void*)g,
                                   (__attribute__((address_space(3))) void*)l, 16, 0, 0);
}

// ---- pack W[k][d][e] (fp32) -> fragment-major bf16 ----
__global__ void pack_w(const float* __restrict__ W, unsigned short* __restrict__ Wp) {
  int idx = blockIdx.x * 256 + threadIdx.x;  // 65536 groups of 8
  int lane = idx & 63, nt = (idx >> 6) & 15, kk = (idx >> 10) & 7, k = idx >> 13;
  const float* src = W + ((size_t)k * HS + kk * 32 + ((lane >> 4) * 8)) * HS + nt * 16 + (lane & 15);
  unsigned short* dst = Wp + (size_t)idx * 8;
#pragma unroll
  for (int i = 0; i < 8; ++i) dst[i] = f2bf(src[(size_t)i * HS]);
}

// ---- fused: ret -> bf16 swizzled tiles (optional) + per-tile column sums; rem sums ----
__global__ void convert_sums(const float* __restrict__ rem, const float* __restrict__ ret,
                             char* __restrict__ swz, float* __restrict__ partial_ret,
                             float* __restrict__ partial_rem) {
  int blk = blockIdx.x, t = threadIdx.x;  // 4096 ret tiles + 512 rem tiles, 256 thr
  const float* src;
  float* pdst;
  char* dst = nullptr;
  if (blk < Bb * Kk * NST) {
    int st = blk & 15, bk = blk >> 4;  // bk = b*K + k
    src = ret + ((size_t)bk * Ss + st * MT) * HS;
    pdst = partial_ret + (size_t)blk * HS;
    if (swz) dst = swz + (size_t)blk * TILE_BYTES;
  } else {
    int rid = blk - Bb * Kk * NST;
    int st = rid & 15, b = rid >> 4;
    src = rem + ((size_t)b * Ss + st * MT) * HS;
    pdst = partial_rem + (size_t)rid * HS;
  }
  f32x4 acc = {0.f, 0.f, 0.f, 0.f};
#pragma unroll
  for (int j = 0; j < 8; ++j) {
    int f = j * 256 + t;
    int row = f >> 6, c4 = f & 63;
    f32x4 v = *reinterpret_cast<const f32x4*>(src + (size_t)row * HS + c4 * 4);
    acc += v;
    if (dst) {
      union { unsigned short h[4]; unsigned long long u; } pk;
      pk.h[0] = f2bf(v[0]); pk.h[1] = f2bf(v[1]); pk.h[2] = f2bf(v[2]); pk.h[3] = f2bf(v[3]);
      // dest layout == desired LDS image: half(8KB) | row*256 | swz granule | 8B half-granule
      int off = (c4 >> 5) * 8192 + row * 256 + ((((c4 & 31) >> 1) ^ (row & 7)) * 16) + (c4 & 1) * 8;
      *reinterpret_cast<unsigned long long*>(dst + off) = pk.u;
    }
  }
  __shared__ f32x4 red[256];
  red[t] = acc;
  __syncthreads();
  if (t < 64) {
    f32x4 s = red[t] + red[t + 64] + red[t + 128] + red[t + 192];
    *reinterpret_cast<f32x4*>(pdst + t * 4) = s;
  }
}

// ---- routing from partial sums ----
__global__ void routing_kernel(const float* __restrict__ partial_ret, const float* __restrict__ partial_rem,
                               const float* __restrict__ Wr, const float* __restrict__ br,
                               const float* __restrict__ Wt, const float* __restrict__ bt,
                               float* __restrict__ routing) {
  int b = blockIdx.x, t = threadIdx.x;  // 256 threads
  __shared__ float srem[HS];
  __shared__ float sret[Kk][HS];
  {
    float s = 0.f;
    for (int st = 0; st < NST; ++st) s += partial_rem[((size_t)(b * NST + st)) * HS + t];
    srem[t] = s;
    for (int k = 0; k < Kk; ++k) {
      float sk = 0.f;
      for (int st = 0; st < NST; ++st) sk += partial_ret[((size_t)((b * Kk + k) * NST + st)) * HS + t];
      sret[k][t] = sk;
    }
  }
  __syncthreads();
  float rl = 0.f;
  for (int e = 0; e < HS; ++e) rl += srem[e] * Wr[(size_t)e * HS + t];
  rl = rl * (1.f / Ss) + br[t];
  float tl[Kk];
#pragma unroll
  for (int k = 0; k < Kk; ++k) tl[k] = 0.f;
  for (int e = 0; e < HS; ++e) {
    float w = Wt[(size_t)e * HS + t];
#pragma unroll
    for (int k = 0; k < Kk; ++k) tl[k] += sret[k][e] * w;
  }
  __shared__ float sh[4];
  __shared__ float scores[Kk];
  for (int k = 0; k < Kk; ++k) {
    float p = rl * (tl[k] * (1.f / Ss) + bt[t]);
#pragma unroll
    for (int off = 32; off; off >>= 1) p += __shfl_down(p, off);
    if ((t & 63) == 0) sh[t >> 6] = p;
    __syncthreads();
    if (t == 0) scores[k] = sh[0] + sh[1] + sh[2] + sh[3];
    __syncthreads();
  }
  if (t == 0) {
    float mx = scores[0];
    for (int k = 1; k < Kk; ++k) mx = fmaxf(mx, scores[k]);
    float s = 0.f, ev[Kk];
    for (int k = 0; k < Kk; ++k) { ev[k] = expf(scores[k] - mx); s += ev[k]; }
    for (int k = 0; k < Kk; ++k) routing[b * Kk + k] = ev[k] / s;
  }
}

// ---- fused experts v3: M=32 tiles, 512 thr (8 waves = 2wm x 4wn), grid 512,
//      A staged via global_load_lds from pre-swizzled bf16 (SRC=0) or fp32+convert (SRC=1) ----
template <int SRC>
__launch_bounds__(512, 4)
__global__ void experts_kernel(const float* __restrict__ ret, const char* __restrict__ ret_swz,
                               const unsigned short* __restrict__ W1p,
                               const unsigned short* __restrict__ W2p,
                               const float* __restrict__ b1, const float* __restrict__ b2,
                               const float* __restrict__ routing, float* __restrict__ out) {
  __shared__ __align__(16) char A_all[TILE_BYTES];   // 16 KB, swizzled image
  __shared__ unsigned short H_lds[MT * HS];          // 16 KB
  const int blk = blockIdx.x;      // b*16 + st
  const int b = blk >> 4, st = blk & 15;
  const int tid = threadIdx.x;
  const int wave = tid >> 6, lane = tid & 63;
  const int wm = wave >> 2, wn = wave & 3;
  const int l15 = lane & 15, l4 = lane >> 4;
  const int r = wm * 16 + l15;  // A/H fragment row for this lane

  auto stage = [&](int k) {
    if constexpr (SRC == 0) {
      const char* tb = ret_swz + ((size_t)((b * Kk + k) * NST + st)) * TILE_BYTES;
#pragma unroll
      for (int i = 0; i < 2; ++i) {
        int c = wave + i * 8;
        gload_lds16(tb + c * 1024 + (size_t)lane * 16, A_all + c * 1024);
      }
    } else {
      const float* src = ret + ((size_t)(b * Kk + k) * Ss + st * MT) * HS;
#pragma unroll
      for (int j = 0; j < 4; ++j) {
        int f = j * 512 + tid;
        int row = f >> 6, c4 = f & 63;
        f32x4 v = *reinterpret_cast<const f32x4*>(src + (size_t)row * HS + c4 * 4);
        union { unsigned short h[4]; unsigned long long u; } pk;
        pk.h[0] = f2bf(v[0]); pk.h[1] = f2bf(v[1]); pk.h[2] = f2bf(v[2]); pk.h[3] = f2bf(v[3]);
        int off = (c4 >> 5) * 8192 + row * 256 + ((((c4 & 31) >> 1) ^ (row & 7)) * 16) + (c4 & 1) * 8;
        *reinterpret_cast<unsigned long long*>(A_all + off) = pk.u;
      }
    }
  };

  float out_acc[4][4];
#pragma unroll
  for (int n = 0; n < 4; ++n)
#pragma unroll
    for (int i = 0; i < 4; ++i) out_acc[n][i] = 0.f;
  const f32x4 zero4 = {0.f, 0.f, 0.f, 0.f};

  stage(0);
  __syncthreads();

  for (int k = 0; k < Kk; ++k) {
    // ---- GEMM1: H = relu(A @ W1[k] + b1[k]) ----
    f32x4 acc1[4];
#pragma unroll
    for (int n = 0; n < 4; ++n) acc1[n] = zero4;
    const unsigned short* W1k = W1p + (size_t)k * 65536;
#pragma unroll
    for (int kk = 0; kk < 8; ++kk) {
      int slot = (((kk & 3) * 4 + l4) ^ (r & 7));
      bf16x8 a = *reinterpret_cast<const bf16x8*>(A_all + (kk >> 2) * 8192 + r * 256 + slot * 16);
      bf16x8 bb[4];
#pragma unroll
      for (int n = 0; n < 4; ++n)
        bb[n] = *reinterpret_cast<const bf16x8*>(W1k + ((size_t)(kk * 16 + wn * 4 + n) * 64 + lane) * 8);
#pragma unroll
      for (int n = 0; n < 4; ++n)
        acc1[n] = __builtin_amdgcn_mfma_f32_16x16x32_bf16(a, bb[n], acc1[n], 0, 0, 0);
    }

    // ---- epilogue1: +b1, relu -> H_lds (bf16, swizzled) ----
#pragma unroll
    for (int n = 0; n < 4; ++n) {
      int col = (wn * 4 + n) * 16 + l15;
      float b1v = b1[k * HS + col];
#pragma unroll
      for (int i = 0; i < 4; ++i) {
        float h = fmaxf(acc1[n][i] + b1v, 0.f);
        int row = wm * 16 + l4 * 4 + i;
        int boff = row * 512 + ((col * 2) ^ ((row & 7) << 4));
        *reinterpret_cast<unsigned short*>(reinterpret_cast<char*>(H_lds) + boff) = f2bf(h);
      }
    }
    __syncthreads();  // H visible; all A reads done

    if (k + 1 < Kk) stage(k + 1);  // prefetch A(k+1), hides under GEMM2

    // ---- GEMM2: E = H @ W2[k] ----
    f32x4 acc2[4];
#pragma unroll
    for (int n = 0; n < 4; ++n) acc2[n] = zero4;
    const unsigned short* W2k = W2p + (size_t)k * 65536;
#pragma unroll
    for (int kk = 0; kk < 8; ++kk) {
      int slot = ((kk * 4 + l4) ^ (r & 7));
      bf16x8 a = *reinterpret_cast<const bf16x8*>(reinterpret_cast<const char*>(H_lds) + r * 512 + slot * 16);
      bf16x8 bb[4];
#pragma unroll
      for (int n = 0; n < 4; ++n)
        bb[n] = *reinterpret_cast<const bf16x8*>(W2k + ((size_t)(kk * 16 + wn * 4 + n) * 64 + lane) * 8);
#pragma unroll
      for (int n = 0; n < 4; ++n)
        acc2[n] = __builtin_amdgcn_mfma_f32_16x16x32_bf16(a, bb[n], acc2[n], 0, 0, 0);
    }

    float rw = routing[b * Kk + k];
#pragma unroll
    for (int n = 0; n < 4; ++n) {
      int col = (wn * 4 + n) * 16 + l15;
      float b2v = b2[k * HS + col];
#pragma unroll
      for (int i = 0; i < 4; ++i) out_acc[n][i] += rw * (acc2[n][i] + b2v);
    }
    __syncthreads();  // drains A(k+1) loads (vmcnt) + H reads done
  }

#pragma unroll
  for (int n = 0; n < 4; ++n)
#pragma unroll
    for (int i = 0; i < 4; ++i) {
      int row = wm * 16 + l4 * 4 + i;
      out[((size_t)b * Ss + st * MT + row) * HS + (wn * 4 + n) * 16 + l15] = out_acc[n][i];
    }
}

extern "C" void kernel_launch(void* const* d_in, const int* in_sizes, int n_in,
                              void* d_out, int out_size, void* d_ws, size_t ws_size,
                              hipStream_t stream) {
  const float* rem = (const float*)d_in[0];
  const float* ret = (const float*)d_in[1];
  const float* Wr  = (const float*)d_in[2];
  const float* br  = (const float*)d_in[3];
  const float* Wt  = (const float*)d_in[4];
  const float* bt  = (const float*)d_in[5];
  const float* W1  = (const float*)d_in[6];
  const float* b1  = (const float*)d_in[7];
  const float* W2  = (const float*)d_in[8];
  const float* b2  = (const float*)d_in[9];
  float* out = (float*)d_out;

  char* w = (char*)d_ws;
  unsigned short* W1p = (unsigned short*)w;                         // 1 MB
  unsigned short* W2p = (unsigned short*)(w + (1u << 20));          // 1 MB
  float* partial_ret  = (float*)(w + (2u << 20));                   // 4 MB (4096 x 256)
  float* partial_rem  = (float*)(w + (6u << 20));                   // 512 KB (512 x 256)
  float* routing      = (float*)(w + (6u << 20) + (512u << 10));    // 1 KB
  char*  ret_swz      = w + (7u << 20);                             // 64 MB

  bool full = ws_size >= ((size_t)71 << 20);

  pack_w<<<256, 256, 0, stream>>>(W1, W1p);
  pack_w<<<256, 256, 0, stream>>>(W2, W2p);
  convert_sums<<<Bb * Kk * NST + Bb * NST, 256, 0, stream>>>(rem, ret, full ? ret_swz : nullptr,
                                                             partial_ret, partial_rem);
  routing_kernel<<<Bb, 256, 0, stream>>>(partial_ret, partial_rem, Wr, br, Wt, bt, routing);
  if (full)
    experts_kernel<0><<<Bb * NST, 512, 0, stream>>>(ret, ret_swz, W1p, W2p, b1, b2, routing, out);
  else
    experts_kernel<1><<<Bb * NST, 512, 0, stream>>>(ret, nullptr, W1p, W2p, b1, b2, routing, out);
}

// Round 4
// 140.838 us; speedup vs baseline: 2.4809x; 2.4809x over previous
//
#include <hip/hip_runtime.h>
#include <hip/hip_bf16.h>

typedef __attribute__((ext_vector_type(8))) short bf16x8;
typedef __attribute__((ext_vector_type(4))) float f32x4;

constexpr int Bb = 32, Kk = 8, Ss = 512, HS = 256;
constexpr int MT = 32;                    // rows per expert tile
constexpr int NST = Ss / MT;              // 16 st tiles per (b,k)
constexpr int TILE_BYTES = MT * HS * 2;   // 16 KB bf16 tile

__device__ __forceinline__ unsigned short f2bf(float f) {
  unsigned int u = __builtin_bit_cast(unsigned int, f);
  u = (u + 0x7FFFu + ((u >> 16) & 1u)) >> 16;
  return (unsigned short)u;
}

__device__ __forceinline__ void gload_lds16(const void* g, void* l) {
  __builtin_amdgcn_global_load_lds((const __attribute__((address_space(1))) void*)g,
                                   (__attribute__((address_space(3))) void*)l, 16, 0, 0);
}

// ---- pack W[k][d][e] (fp32) -> fragment-major bf16 (B-operand frags; same bytes
//      also serve as A-operand frags of W^T) ----
__global__ void pack_w(const float* __restrict__ W, unsigned short* __restrict__ Wp) {
  int idx = blockIdx.x * 256 + threadIdx.x;  // 65536 groups of 8
  int lane = idx & 63, nt = (idx >> 6) & 15, kk = (idx >> 10) & 7, k = idx >> 13;
  const float* src = W + ((size_t)k * HS + kk * 32 + ((lane >> 4) * 8)) * HS + nt * 16 + (lane & 15);
  unsigned short* dst = Wp + (size_t)idx * 8;
#pragma unroll
  for (int i = 0; i < 8; ++i) dst[i] = f2bf(src[(size_t)i * HS]);
}

// ---- fused: ret -> bf16 swizzled tiles (optional) + per-tile column sums; rem sums ----
__global__ void convert_sums(const float* __restrict__ rem, const float* __restrict__ ret,
                             char* __restrict__ swz, float* __restrict__ partial_ret,
                             float* __restrict__ partial_rem) {
  int blk = blockIdx.x, t = threadIdx.x;  // 4096 ret tiles + 512 rem tiles, 256 thr
  const float* src;
  float* pdst;
  char* dst = nullptr;
  if (blk < Bb * Kk * NST) {
    int st = blk & 15, bk = blk >> 4;  // bk = b*K + k
    src = ret + ((size_t)bk * Ss + st * MT) * HS;
    pdst = partial_ret + (size_t)blk * HS;
    if (swz) dst = swz + (size_t)blk * TILE_BYTES;
  } else {
    int rid = blk - Bb * Kk * NST;
    int st = rid & 15, b = rid >> 4;
    src = rem + ((size_t)b * Ss + st * MT) * HS;
    pdst = partial_rem + (size_t)rid * HS;
  }
  f32x4 acc = {0.f, 0.f, 0.f, 0.f};
#pragma unroll
  for (int j = 0; j < 8; ++j) {
    int f = j * 256 + t;
    int row = f >> 6, c4 = f & 63;
    f32x4 v = *reinterpret_cast<const f32x4*>(src + (size_t)row * HS + c4 * 4);
    acc += v;
    if (dst) {
      union { unsigned short h[4]; unsigned long long u; } pk;
      pk.h[0] = f2bf(v[0]); pk.h[1] = f2bf(v[1]); pk.h[2] = f2bf(v[2]); pk.h[3] = f2bf(v[3]);
      int off = (c4 >> 5) * 8192 + row * 256 + ((((c4 & 31) >> 1) ^ (row & 7)) * 16) + (c4 & 1) * 8;
      *reinterpret_cast<unsigned long long*>(dst + off) = pk.u;
    }
  }
  __shared__ f32x4 red[256];
  red[t] = acc;
  __syncthreads();
  if (t < 64) {
    f32x4 s = red[t] + red[t + 64] + red[t + 128] + red[t + 192];
    *reinterpret_cast<f32x4*>(pdst + t * 4) = s;
  }
}

// ---- routing from partial sums ----
__global__ void routing_kernel(const float* __restrict__ partial_ret, const float* __restrict__ partial_rem,
                               const float* __restrict__ Wr, const float* __restrict__ br,
                               const float* __restrict__ Wt, const float* __restrict__ bt,
                               float* __restrict__ routing) {
  int b = blockIdx.x, t = threadIdx.x;  // 256 threads
  __shared__ float srem[HS];
  __shared__ float sret[Kk][HS];
  {
    float s = 0.f;
    for (int st = 0; st < NST; ++st) s += partial_rem[((size_t)(b * NST + st)) * HS + t];
    srem[t] = s;
    for (int k = 0; k < Kk; ++k) {
      float sk = 0.f;
      for (int st = 0; st < NST; ++st) sk += partial_ret[((size_t)((b * Kk + k) * NST + st)) * HS + t];
      sret[k][t] = sk;
    }
  }
  __syncthreads();
  float rl = 0.f;
  for (int e = 0; e < HS; ++e) rl += srem[e] * Wr[(size_t)e * HS + t];
  rl = rl * (1.f / Ss) + br[t];
  float tl[Kk];
#pragma unroll
  for (int k = 0; k < Kk; ++k) tl[k] = 0.f;
  for (int e = 0; e < HS; ++e) {
    float w = Wt[(size_t)e * HS + t];
#pragma unroll
    for (int k = 0; k < Kk; ++k) tl[k] += sret[k][e] * w;
  }
  __shared__ float sh[4];
  __shared__ float scores[Kk];
  for (int k = 0; k < Kk; ++k) {
    float p = rl * (tl[k] * (1.f / Ss) + bt[t]);
#pragma unroll
    for (int off = 32; off; off >>= 1) p += __shfl_down(p, off);
    if ((t & 63) == 0) sh[t >> 6] = p;
    __syncthreads();
    if (t == 0) scores[k] = sh[0] + sh[1] + sh[2] + sh[3];
    __syncthreads();
  }
  if (t == 0) {
    float mx = scores[0];
    for (int k = 1; k < Kk; ++k) mx = fmaxf(mx, scores[k]);
    float s = 0.f, ev[Kk];
    for (int k = 0; k < Kk; ++k) { ev[k] = expf(scores[k] - mx); s += ev[k]; }
    for (int k = 0; k < Kk; ++k) routing[b * Kk + k] = ev[k] / s;
  }
}

// ---- fused experts v4: 256 thr (4 waves), 64-wide wave tiles on both GEMMs.
//      GEMM1 computed transposed: H^T = W1^T * A^T (W frags double as A-operand;
//      A-tile reads double as B-operand; C gives 4 consecutive H-cols/lane -> b64 writes).
//      A double-buffered, staged via global_load_lds (SRC=0) or reg-convert (SRC=1). ----
template <int SRC>
__launch_bounds__(256, 1)
__global__ void experts_kernel(const float* __restrict__ ret, const char* __restrict__ ret_swz,
                               const unsigned short* __restrict__ W1p,
                               const unsigned short* __restrict__ W2p,
                               const float* __restrict__ b1, const float* __restrict__ b2,
                               const float* __restrict__ routing, float* __restrict__ out) {
  __shared__ __align__(16) char A_lds[2][TILE_BYTES];   // 2 x 16 KB swizzled image
  __shared__ __align__(16) char H_lds[TILE_BYTES];      // 16 KB, row*512B, XOR-swizzled
  const int blk = blockIdx.x;      // b*16 + st
  const int b = blk >> 4, st = blk & 15;
  const int tid = threadIdx.x;
  const int wave = tid >> 6, lane = tid & 63;
  const int l15 = lane & 15, l4 = lane >> 4;

  auto stage = [&](int k, int bufi) {
    if constexpr (SRC == 0) {
      const char* tb = ret_swz + ((size_t)((b * Kk + k) * NST + st)) * TILE_BYTES;
#pragma unroll
      for (int i = 0; i < 4; ++i) {
        int c = wave + i * 4;
        gload_lds16(tb + c * 1024 + (size_t)lane * 16, A_lds[bufi] + c * 1024);
      }
    } else {
      const float* src = ret + ((size_t)(b * Kk + k) * Ss + st * MT) * HS;
#pragma unroll
      for (int j = 0; j < 8; ++j) {
        int f = j * 256 + tid;
        int row = f >> 6, c4 = f & 63;
        f32x4 v = *reinterpret_cast<const f32x4*>(src + (size_t)row * HS + c4 * 4);
        union { unsigned short h[4]; unsigned long long u; } pk;
        pk.h[0] = f2bf(v[0]); pk.h[1] = f2bf(v[1]); pk.h[2] = f2bf(v[2]); pk.h[3] = f2bf(v[3]);
        int off = (c4 >> 5) * 8192 + row * 256 + ((((c4 & 31) >> 1) ^ (row & 7)) * 16) + (c4 & 1) * 8;
        *reinterpret_cast<unsigned long long*>(A_lds[bufi] + off) = pk.u;
      }
    }
  };

  float out_acc[2][4][4];
#pragma unroll
  for (int m = 0; m < 2; ++m)
#pragma unroll
    for (int n = 0; n < 4; ++n)
#pragma unroll
      for (int i = 0; i < 4; ++i) out_acc[m][n][i] = 0.f;
  const f32x4 zero4 = {0.f, 0.f, 0.f, 0.f};

  stage(0, 0);
  __syncthreads();

  int buf = 0;
  for (int k = 0; k < Kk; ++k) {
    if (k + 1 < Kk) stage(k + 1, buf ^ 1);  // issue first; hides under GEMM1'

    // ---- GEMM1': H^T = W1^T(A-op) x A^T(B-op); wave owns e in [wave*64, wave*64+64) ----
    f32x4 accH[4][2];
#pragma unroll
    for (int m = 0; m < 4; ++m)
#pragma unroll
      for (int n = 0; n < 2; ++n) accH[m][n] = zero4;

    const unsigned short* W1k = W1p + (size_t)k * 65536;
#pragma unroll
    for (int kk = 0; kk < 8; ++kk) {
      bf16x8 aW[4], aA[2];
#pragma unroll
      for (int m = 0; m < 4; ++m)
        aW[m] = *reinterpret_cast<const bf16x8*>(W1k + ((size_t)(kk * 16 + wave * 4 + m) * 64 + lane) * 8);
#pragma unroll
      for (int n = 0; n < 2; ++n) {
        int r = n * 16 + l15;
        int slot = (((kk & 3) * 4 + l4) ^ (r & 7));
        aA[n] = *reinterpret_cast<const bf16x8*>(A_lds[buf] + (kk >> 2) * 8192 + r * 256 + slot * 16);
      }
#pragma unroll
      for (int m = 0; m < 4; ++m)
#pragma unroll
        for (int n = 0; n < 2; ++n)
          accH[m][n] = __builtin_amdgcn_mfma_f32_16x16x32_bf16(aW[m], aA[n], accH[m][n], 0, 0, 0);
    }

    // ---- epilogue1': +b1, relu; lane holds 4 consecutive H-cols -> ds_write_b64 ----
#pragma unroll
    for (int m = 0; m < 4; ++m) {
      int e0 = wave * 64 + m * 16 + l4 * 4;  // H-col base (4 consecutive)
      float4 b1v = *reinterpret_cast<const float4*>(b1 + k * HS + e0);
#pragma unroll
      for (int n = 0; n < 2; ++n) {
        int srow = n * 16 + l15;
        union { unsigned short h[4]; unsigned long long u; } pk;
        pk.h[0] = f2bf(fmaxf(accH[m][n][0] + b1v.x, 0.f));
        pk.h[1] = f2bf(fmaxf(accH[m][n][1] + b1v.y, 0.f));
        pk.h[2] = f2bf(fmaxf(accH[m][n][2] + b1v.z, 0.f));
        pk.h[3] = f2bf(fmaxf(accH[m][n][3] + b1v.w, 0.f));
        int boff = srow * 512 + ((e0 * 2) ^ ((srow & 7) << 4));
        *reinterpret_cast<unsigned long long*>(H_lds + boff) = pk.u;
      }
    }
    __syncthreads();  // H visible (also drains A(k+1) staging early - harmless)

    // ---- GEMM2: out-tile += routing * (H x W2 + b2); wave owns cols [wave*64, +64) ----
    f32x4 acc2[2][4];
#pragma unroll
    for (int m = 0; m < 2; ++m)
#pragma unroll
      for (int n = 0; n < 4; ++n) acc2[m][n] = zero4;

    const unsigned short* W2k = W2p + (size_t)k * 65536;
#pragma unroll
    for (int kk = 0; kk < 8; ++kk) {
      bf16x8 aH[2], bW[4];
#pragma unroll
      for (int m = 0; m < 2; ++m) {
        int r = m * 16 + l15;
        int boff = r * 512 + ((kk * 64 + l4 * 16) ^ ((r & 7) << 4));
        aH[m] = *reinterpret_cast<const bf16x8*>(H_lds + boff);
      }
#pragma unroll
      for (int n = 0; n < 4; ++n)
        bW[n] = *reinterpret_cast<const bf16x8*>(W2k + ((size_t)(kk * 16 + wave * 4 + n) * 64 + lane) * 8);
#pragma unroll
      for (int m = 0; m < 2; ++m)
#pragma unroll
        for (int n = 0; n < 4; ++n)
          acc2[m][n] = __builtin_amdgcn_mfma_f32_16x16x32_bf16(aH[m], bW[n], acc2[m][n], 0, 0, 0);
    }

    float rw = routing[b * Kk + k];
#pragma unroll
    for (int n = 0; n < 4; ++n) {
      int col = (wave * 4 + n) * 16 + l15;
      float b2v = b2[k * HS + col];
#pragma unroll
      for (int m = 0; m < 2; ++m)
#pragma unroll
        for (int i = 0; i < 4; ++i) out_acc[m][n][i] += rw * (acc2[m][n][i] + b2v);
    }
    __syncthreads();  // H reads done before next epilogue write; A(k+1) complete
    buf ^= 1;
  }

#pragma unroll
  for (int m = 0; m < 2; ++m)
#pragma unroll
    for (int i = 0; i < 4; ++i) {
      int row = m * 16 + l4 * 4 + i;
      float* orow = out + ((size_t)b * Ss + st * MT + row) * HS;
#pragma unroll
      for (int n = 0; n < 4; ++n) orow[(wave * 4 + n) * 16 + l15] = out_acc[m][n][i];
    }
}

extern "C" void kernel_launch(void* const* d_in, const int* in_sizes, int n_in,
                              void* d_out, int out_size, void* d_ws, size_t ws_size,
                              hipStream_t stream) {
  const float* rem = (const float*)d_in[0];
  const float* ret = (const float*)d_in[1];
  const float* Wr  = (const float*)d_in[2];
  const float* br  = (const float*)d_in[3];
  const float* Wt  = (const float*)d_in[4];
  const float* bt  = (const float*)d_in[5];
  const float* W1  = (const float*)d_in[6];
  const float* b1  = (const float*)d_in[7];
  const float* W2  = (const float*)d_in[8];
  const float* b2  = (const float*)d_in[9];
  float* out = (float*)d_out;

  char* w = (char*)d_ws;
  unsigned short* W1p = (unsigned short*)w;                         // 1 MB
  unsigned short* W2p = (unsigned short*)(w + (1u << 20));          // 1 MB
  float* partial_ret  = (float*)(w + (2u << 20));                   // 4 MB (4096 x 256)
  float* partial_rem  = (float*)(w + (6u << 20));                   // 512 KB (512 x 256)
  float* routing      = (float*)(w + (6u << 20) + (512u << 10));    // 1 KB
  char*  ret_swz      = w + (7u << 20);                             // 64 MB

  bool full = ws_size >= ((size_t)71 << 20);

  pack_w<<<256, 256, 0, stream>>>(W1, W1p);
  pack_w<<<256, 256, 0, stream>>>(W2, W2p);
  convert_sums<<<Bb * Kk * NST + Bb * NST, 256, 0, stream>>>(rem, ret, full ? ret_swz : nullptr,
                                                             partial_ret, partial_rem);
  routing_kernel<<<Bb, 256, 0, stream>>>(partial_ret, partial_rem, Wr, br, Wt, bt, routing);
  if (full)
    experts_kernel<0><<<Bb * NST, 256, 0, stream>>>(ret, ret_swz, W1p, W2p, b1, b2, routing, out);
  else
    experts_kernel<1><<<Bb * NST, 256, 0, stream>>>(ret, nullptr, W1p, W2p, b1, b2, routing, out);
}